// Round 2
// baseline (997.335 us; speedup 1.0000x reference)
//
#include <hip/hip_runtime.h>

typedef short bf16x8 __attribute__((ext_vector_type(8)));
typedef float f32x4 __attribute__((ext_vector_type(4)));

#define DD 512
#define NG 512

// split f32 into bf16 hi (truncate) + bf16 lo (round) ; f ≈ hi + lo with ~2^-16 rel err
static __device__ __forceinline__ void cvt_hl(float f, unsigned short& h, unsigned short& l) {
  unsigned u = __builtin_bit_cast(unsigned, f);
  unsigned hu = u & 0xffff0000u;
  float fh = __builtin_bit_cast(float, hu);
  float fl = f - fh;                       // exact in f32
  unsigned ul = __builtin_bit_cast(unsigned, fl);
  h = (unsigned short)(hu >> 16);
  l = (unsigned short)((ul + 0x8000u) >> 16);
}

// fast tanh: 1 - 2/(e^{2v}+1), native exp/rcp (~1e-6 abs err, saturates correctly)
static __device__ __forceinline__ float fast_tanh(float v) {
  float e = __expf(2.0f * v);
  return 1.0f - 2.0f * __builtin_amdgcn_rcpf(e + 1.0f);
}

// W [512][512] f32 -> packed per row: 64 kgroups x [8 hi bf16 | 8 lo bf16]
__global__ __launch_bounds__(256) void k_convert_w(const float* __restrict__ W,
                                                   unsigned short* __restrict__ Whl) {
  int t = blockIdx.x * 256 + threadIdx.x;   // 32768 tasks
  int row = t >> 6, kg = t & 63;
  const float* p = W + row * DD + kg * 8;
  unsigned short h[8], l[8];
#pragma unroll
  for (int j = 0; j < 8; ++j) cvt_hl(p[j], h[j], l[j]);
  unsigned short* q = Whl + row * (DD * 2) + kg * 16;
#pragma unroll
  for (int j = 0; j < 8; ++j) { q[j] = h[j]; q[8 + j] = l[j]; }
}

// Fused: y = x @ W^T + b ; score = tanh(y) @ query.  One wave = 16 rows, all 512 cols in acc.
__global__ __launch_bounds__(256, 2) void k_gemm_score(
    const float* __restrict__ x, const unsigned short* __restrict__ Whl,
    const float* __restrict__ bias, const float* __restrict__ query,
    float* __restrict__ score) {
  const int tid = threadIdx.x;
  const int wave = tid >> 6;
  const int lane = tid & 63;
  const int l15 = lane & 15;
  const int lg = lane >> 4;
  const int row0 = blockIdx.x * 64 + wave * 16;

  const float* xp = x + (size_t)(row0 + l15) * DD + lg * 8;
  const unsigned short* wp = Whl + l15 * (DD * 2) + lg * 16;

  f32x4 acc[32];
#pragma unroll
  for (int ct = 0; ct < 32; ++ct) acc[ct] = (f32x4){0.f, 0.f, 0.f, 0.f};

  for (int kt = 0; kt < 16; ++kt) {
    // A fragment: 8 consecutive f32 of this lane's row, split hi/lo
    const float4 a0 = *(const float4*)(xp + kt * 32);
    const float4 a1 = *(const float4*)(xp + kt * 32 + 4);
    float af[8] = {a0.x, a0.y, a0.z, a0.w, a1.x, a1.y, a1.z, a1.w};
    bf16x8 ah, al;
#pragma unroll
    for (int j = 0; j < 8; ++j) {
      unsigned short h, l;
      cvt_hl(af[j], h, l);
      ah[j] = (short)h;
      al[j] = (short)l;
    }
    const unsigned short* wk = wp + kt * 64;   // kgroup stride within a row-pack
#pragma unroll
    for (int ct = 0; ct < 32; ++ct) {
      const unsigned short* p = wk + ct * 16384;   // 16 W-rows * 1024 elems
      bf16x8 bh = *(const bf16x8*)(p);
      bf16x8 bl = *(const bf16x8*)(p + 8);
      acc[ct] = __builtin_amdgcn_mfma_f32_16x16x32_bf16(ah, bh, acc[ct], 0, 0, 0);
      acc[ct] = __builtin_amdgcn_mfma_f32_16x16x32_bf16(al, bh, acc[ct], 0, 0, 0);
      acc[ct] = __builtin_amdgcn_mfma_f32_16x16x32_bf16(ah, bl, acc[ct], 0, 0, 0);
    }
  }

  // epilogue: tanh + dot with query, reduce across the 16 lanes of each row-group
  float sp[4] = {0.f, 0.f, 0.f, 0.f};
#pragma unroll
  for (int ct = 0; ct < 32; ++ct) {
    const int col = ct * 16 + l15;
    const float bb = bias[col];
    const float qq = query[col];
#pragma unroll
    for (int r = 0; r < 4; ++r) {
      float t = fast_tanh(acc[ct][r] + bb);
      sp[r] += t * qq;
    }
  }
#pragma unroll
  for (int r = 0; r < 4; ++r) {
    float v = sp[r];
    v += __shfl_xor(v, 1);
    v += __shfl_xor(v, 2);
    v += __shfl_xor(v, 4);
    v += __shfl_xor(v, 8);
    if (l15 == 0) score[row0 + lg * 4 + r] = v;   // C row = lg*4 + r
  }
}

// Per-graph: segmented softmax over score + weighted sum of x rows -> out[g][512]
// graph_ptr dtype probed at runtime (harness may pass int32 or int64).
__global__ __launch_bounds__(256) void k_softmax_out(
    const float* __restrict__ x, const void* __restrict__ segp,
    const float* __restrict__ score, float* __restrict__ out, int N) {
  const int g = blockIdx.x;
  const int tid = threadIdx.x;

  // dtype probe: if the buffer is int64, element N/2-1 is a graph id (<NG).
  // If it's int32, that 8-byte word combines two ids from the sorted tail
  // (~511 + 511*2^32) -> huge. Never reads past min(4N, 8*(N/2)) bytes.
  const long long probe = ((const long long*)segp)[N / 2 - 1];
  const bool is64 = ((unsigned long long)probe < (unsigned long long)NG);
  const long long* s64 = (const long long*)segp;
  const int* s32 = (const int*)segp;

  // binary search segment bounds (graph_ptr sorted)
  int s0, s1;
  {
    int lo = 0, hi = N;
    while (lo < hi) {
      int m = (lo + hi) >> 1;
      long long v = is64 ? s64[m] : (long long)s32[m];
      if (v < (long long)g) lo = m + 1; else hi = m;
    }
    s0 = lo;
    lo = s0; hi = N;
    while (lo < hi) {
      int m = (lo + hi) >> 1;
      long long v = is64 ? s64[m] : (long long)s32[m];
      if (v < (long long)(g + 1)) lo = m + 1; else hi = m;
    }
    s1 = lo;
  }

  __shared__ float red[4];
  __shared__ float wbuf[512];

  float lm = -INFINITY;
  for (int i = s0 + tid; i < s1; i += 256) lm = fmaxf(lm, score[i]);
#pragma unroll
  for (int m = 1; m < 64; m <<= 1) lm = fmaxf(lm, __shfl_xor(lm, m));
  if ((tid & 63) == 0) red[tid >> 6] = lm;
  __syncthreads();
  const float mx = fmaxf(fmaxf(red[0], red[1]), fmaxf(red[2], red[3]));
  __syncthreads();

  float ls = 0.f;
  for (int i = s0 + tid; i < s1; i += 256) ls += expf(score[i] - mx);
#pragma unroll
  for (int m = 1; m < 64; m <<= 1) ls += __shfl_xor(ls, m);
  if ((tid & 63) == 0) red[tid >> 6] = ls;
  __syncthreads();
  const float sum = red[0] + red[1] + red[2] + red[3];
  const float inv = sum > 0.f ? 1.0f / sum : 0.f;

  float a0 = 0.f, a1 = 0.f;
  const int c = tid * 2;
  for (int base = s0; base < s1; base += 512) {
    const int cnt = min(512, s1 - base);
    __syncthreads();
    for (int i = tid; i < cnt; i += 256) wbuf[i] = expf(score[base + i] - mx) * inv;
    __syncthreads();
#pragma unroll 4
    for (int j = 0; j < cnt; ++j) {
      const float w = wbuf[j];
      const float2 xv = *(const float2*)(x + (size_t)(base + j) * DD + c);
      a0 = fmaf(w, xv.x, a0);
      a1 = fmaf(w, xv.y, a1);
    }
  }
  float* op = out + (size_t)g * DD + c;
  op[0] = a0;
  op[1] = a1;
}

extern "C" void kernel_launch(void* const* d_in, const int* in_sizes, int n_in,
                              void* d_out, int out_size, void* d_ws, size_t ws_size,
                              hipStream_t stream) {
  const float* x = (const float*)d_in[0];
  const void* seg = d_in[1];
  const float* W = (const float*)d_in[2];
  const float* b = (const float*)d_in[3];
  const float* q = (const float*)d_in[4];
  float* out = (float*)d_out;
  const int N = in_sizes[0] / DD;  // 131072

  unsigned short* Whl = (unsigned short*)d_ws;                       // 512*1024 bf16 = 1 MB
  float* score = (float*)((char*)d_ws + (size_t)DD * DD * 2 * 2);    // +1 MB

  k_convert_w<<<128, 256, 0, stream>>>(W, Whl);
  k_gemm_score<<<N / 64, 256, 0, stream>>>(x, Whl, b, q, score);
  k_softmax_out<<<NG, 256, 0, stream>>>(x, seg, score, out, N);
}

// Round 3
// 259.019 us; speedup vs baseline: 3.8504x; 3.8504x over previous
//
#include <hip/hip_runtime.h>

typedef short bf16x8 __attribute__((ext_vector_type(8)));
typedef short short8 __attribute__((ext_vector_type(8)));
typedef float f32x4 __attribute__((ext_vector_type(4)));

#define DD 512
#define NG 512

typedef __attribute__((address_space(3))) void lds_void;
typedef __attribute__((address_space(1))) void glb_void;

static __device__ __forceinline__ void gload_lds16(const void* g, void* l) {
  __builtin_amdgcn_global_load_lds((const glb_void*)g, (lds_void*)l, 16, 0, 0);
}

// split f32 into bf16 hi (truncate) + bf16 lo (round) ; f ≈ hi + lo with ~2^-16 rel err
static __device__ __forceinline__ void cvt_hl(float f, unsigned short& h, unsigned short& l) {
  unsigned u = __builtin_bit_cast(unsigned, f);
  unsigned hu = u & 0xffff0000u;
  float fh = __builtin_bit_cast(float, hu);
  float fl = f - fh;                       // exact in f32
  unsigned ul = __builtin_bit_cast(unsigned, fl);
  h = (unsigned short)(hu >> 16);
  l = (unsigned short)((ul + 0x8000u) >> 16);
}

// fast tanh: 1 - 2/(e^{2v}+1), native exp/rcp (~1e-6 abs err, saturates correctly)
static __device__ __forceinline__ float fast_tanh(float v) {
  float e = __expf(2.0f * v);
  return 1.0f - 2.0f * __builtin_amdgcn_rcpf(e + 1.0f);
}

// W [512][512] f32 -> swizzled hi/lo bf16 pack, organized as
// [ny(2)][kt(16)][32KB slice], slice: row r(0..255), kgrel(0..3), hl, e:
//   off = (r*128 + kgrel*32 + hl*16 + e*2) ^ ((r&7)<<4)
// The XOR pre-swizzle makes the linear global_load_lds staging produce a
// bank-conflict-free layout for the ds_read_b128 pattern in k_gemm_score.
__global__ __launch_bounds__(256) void k_convert_w(const float* __restrict__ W,
                                                   unsigned char* __restrict__ Whl) {
  int t = blockIdx.x * 256 + threadIdx.x;   // 32768 tasks
  int r512 = t >> 6, kg = t & 63;           // W row (out col), kgroup of 8 k
  int ny = r512 >> 8, r = r512 & 255;
  int kt = kg >> 2, kgrel = kg & 3;
  const float* p = W + (size_t)r512 * DD + kg * 8;
  short8 h, l;
#pragma unroll
  for (int j = 0; j < 8; ++j) {
    unsigned short hh, ll;
    cvt_hl(p[j], hh, ll);
    h[j] = (short)hh;
    l[j] = (short)ll;
  }
  size_t base = (size_t)ny * 524288 + (size_t)kt * 32768;
  int u = (r * 128 + kgrel * 32) ^ ((r & 7) << 4);
  *(short8*)(Whl + base + u) = h;
  *(short8*)(Whl + base + (u ^ 16)) = l;
}

// Fused GEMM + gate + partial score.  Block: 8 waves x 16 rows = 128 rows,
// 256 cols (blockIdx.y half).  B staged in LDS (32KB/slice, double-buffered),
// A (x) streamed per-lane, converted to bf16 hi/lo in-register.
__global__ __launch_bounds__(512, 2) void k_gemm_score(
    const float* __restrict__ x, const unsigned char* __restrict__ Whl,
    const float* __restrict__ bias, const float* __restrict__ query,
    float* __restrict__ score_part, int N) {
  __shared__ unsigned char lds[2][32768];
  const int tid = threadIdx.x;
  const int wave = tid >> 6;
  const int lane = tid & 63;
  const int l15 = lane & 15;
  const int lg = lane >> 4;
  const int ny = blockIdx.y;
  const int row0 = blockIdx.x * 128 + wave * 16;

  const float4* xp = (const float4*)(x + (size_t)(row0 + l15) * DD + lg * 8);
  const unsigned char* wsrc = Whl + (size_t)ny * 524288 + wave * 1024 + lane * 16;
  const int swz = (l15 & 7) << 4;

  f32x4 acc[16];
#pragma unroll
  for (int ct = 0; ct < 16; ++ct) acc[ct] = (f32x4){0.f, 0.f, 0.f, 0.f};

  // prologue: stage slice 0
  {
    const unsigned char* src = wsrc;
#pragma unroll
    for (int i = 0; i < 4; ++i)
      gload_lds16(src + i * 8192, &lds[0][wave * 1024 + i * 8192]);
  }
  __syncthreads();

  for (int kt = 0; kt < 16; ++kt) {
    const int cur = kt & 1;
    if (kt < 15) {  // stage next slice into the other buffer (in flight during compute)
      const unsigned char* src = wsrc + (size_t)(kt + 1) * 32768;
#pragma unroll
      for (int i = 0; i < 4; ++i)
        gload_lds16(src + i * 8192, &lds[cur ^ 1][wave * 1024 + i * 8192]);
    }

    // A fragment: 8 consecutive f32 of this lane's row, split hi/lo
    const float4 a0 = xp[kt * 8];
    const float4 a1 = xp[kt * 8 + 1];
    float af[8] = {a0.x, a0.y, a0.z, a0.w, a1.x, a1.y, a1.z, a1.w};
    bf16x8 ah, al;
#pragma unroll
    for (int j = 0; j < 8; ++j) {
      unsigned short hh, ll;
      cvt_hl(af[j], hh, ll);
      ah[j] = (short)hh;
      al[j] = (short)ll;
    }

    const unsigned char* bb = &lds[cur][0];
#pragma unroll
    for (int ct = 0; ct < 16; ++ct) {
      const int u = (((l15 + 16 * ct) * 128) + lg * 32) ^ swz;
      bf16x8 bh = *(const bf16x8*)(bb + u);
      bf16x8 bl = *(const bf16x8*)(bb + (u ^ 16));
      acc[ct] = __builtin_amdgcn_mfma_f32_16x16x32_bf16(ah, bh, acc[ct], 0, 0, 0);
      acc[ct] = __builtin_amdgcn_mfma_f32_16x16x32_bf16(al, bh, acc[ct], 0, 0, 0);
      acc[ct] = __builtin_amdgcn_mfma_f32_16x16x32_bf16(ah, bl, acc[ct], 0, 0, 0);
    }
    __syncthreads();   // drains stage loads (vmcnt 0) + protects buffer reuse
  }

  // epilogue: tanh + dot with query over this block's 256 cols
  float sp[4] = {0.f, 0.f, 0.f, 0.f};
#pragma unroll
  for (int ct = 0; ct < 16; ++ct) {
    const int col = ny * 256 + ct * 16 + l15;
    const float bb = bias[col];
    const float qq = query[col];
#pragma unroll
    for (int r = 0; r < 4; ++r) {
      float t = fast_tanh(acc[ct][r] + bb);
      sp[r] += t * qq;
    }
  }
#pragma unroll
  for (int r = 0; r < 4; ++r) {
    float v = sp[r];
    v += __shfl_xor(v, 1);
    v += __shfl_xor(v, 2);
    v += __shfl_xor(v, 4);
    v += __shfl_xor(v, 8);
    if (l15 == 0) score_part[(size_t)ny * N + row0 + lg * 4 + r] = v;  // C row = lg*4 + r
  }
}

// Per-graph: segmented softmax over (sp0+sp1) + weighted sum of x rows -> out[g][512]
__global__ __launch_bounds__(256) void k_softmax_out(
    const float* __restrict__ x, const void* __restrict__ segp,
    const float* __restrict__ sp0, const float* __restrict__ sp1,
    float* __restrict__ out, int N) {
  const int g = blockIdx.x;
  const int tid = threadIdx.x;

  // dtype probe: int64 element N/2-1 is a graph id (<NG) iff buffer is int64.
  const long long probe = ((const long long*)segp)[N / 2 - 1];
  const bool is64 = ((unsigned long long)probe < (unsigned long long)NG);
  const long long* s64 = (const long long*)segp;
  const int* s32 = (const int*)segp;

  int s0, s1;
  {
    int lo = 0, hi = N;
    while (lo < hi) {
      int m = (lo + hi) >> 1;
      long long v = is64 ? s64[m] : (long long)s32[m];
      if (v < (long long)g) lo = m + 1; else hi = m;
    }
    s0 = lo;
    lo = s0; hi = N;
    while (lo < hi) {
      int m = (lo + hi) >> 1;
      long long v = is64 ? s64[m] : (long long)s32[m];
      if (v < (long long)(g + 1)) lo = m + 1; else hi = m;
    }
    s1 = lo;
  }

  __shared__ float red[4];
  __shared__ float wbuf[512];

  float lm = -INFINITY;
  for (int i = s0 + tid; i < s1; i += 256) lm = fmaxf(lm, sp0[i] + sp1[i]);
#pragma unroll
  for (int m = 1; m < 64; m <<= 1) lm = fmaxf(lm, __shfl_xor(lm, m));
  if ((tid & 63) == 0) red[tid >> 6] = lm;
  __syncthreads();
  const float mx = fmaxf(fmaxf(red[0], red[1]), fmaxf(red[2], red[3]));
  __syncthreads();

  float ls = 0.f;
  for (int i = s0 + tid; i < s1; i += 256) ls += expf(sp0[i] + sp1[i] - mx);
#pragma unroll
  for (int m = 1; m < 64; m <<= 1) ls += __shfl_xor(ls, m);
  if ((tid & 63) == 0) red[tid >> 6] = ls;
  __syncthreads();
  const float sum = red[0] + red[1] + red[2] + red[3];
  const float inv = sum > 0.f ? 1.0f / sum : 0.f;

  float a0 = 0.f, a1 = 0.f;
  const int c = tid * 2;
  for (int base = s0; base < s1; base += 512) {
    const int cnt = min(512, s1 - base);
    __syncthreads();
    for (int i = tid; i < cnt; i += 256)
      wbuf[i] = expf(sp0[base + i] + sp1[base + i] - mx) * inv;
    __syncthreads();
#pragma unroll 4
    for (int j = 0; j < cnt; ++j) {
      const float w = wbuf[j];
      const float2 xv = *(const float2*)(x + (size_t)(base + j) * DD + c);
      a0 = fmaf(w, xv.x, a0);
      a1 = fmaf(w, xv.y, a1);
    }
  }
  float* op = out + (size_t)g * DD + c;
  op[0] = a0;
  op[1] = a1;
}

extern "C" void kernel_launch(void* const* d_in, const int* in_sizes, int n_in,
                              void* d_out, int out_size, void* d_ws, size_t ws_size,
                              hipStream_t stream) {
  const float* x = (const float*)d_in[0];
  const void* seg = d_in[1];
  const float* W = (const float*)d_in[2];
  const float* b = (const float*)d_in[3];
  const float* q = (const float*)d_in[4];
  float* out = (float*)d_out;
  const int N = in_sizes[0] / DD;  // 131072

  unsigned char* Whl = (unsigned char*)d_ws;                 // 1 MB packed+swizzled W
  float* sp0 = (float*)(Whl + 1048576);                      // N partial scores (ny=0)
  float* sp1 = sp0 + N;                                      // N partial scores (ny=1)

  k_convert_w<<<128, 256, 0, stream>>>(W, Whl);
  dim3 grid(N / 128, 2);
  k_gemm_score<<<grid, 512, 0, stream>>>(x, Whl, b, q, sp0, N);
  k_softmax_out<<<NG, 256, 0, stream>>>(x, seg, sp0, sp1, out, N);
}